// Round 2
// baseline (104.164 us; speedup 1.0000x reference)
//
#include <hip/hip_runtime.h>
#include <hip/hip_bf16.h>
#include <math.h>

// Batch-hard triplet loss, B=8192, D=128, fp32 in.
// dist^2[i,j] = rowterm[i] + colterm[j] - 2*dot(e1[i], e2[j])
// sqrt & max/min commute -> track max/min of (colterm - 2*dot); dot on bf16
// matrix cores. Target folded into cpos/cneg (finite +-1e30 sentinels).
//
// R9 vs R8: dispatch-structure round. R8's tile destall was NEUTRAL -> tile
// kernel is a minor term (~5-7 us model); the remaining ~49 us (beyond the
// 42 us harness ws re-poison fill) is launch gaps + underfilled helper
// kernels. (1) reduce_kernel FUSED into tile kernel: last-of-8 split blocks
// per row-block (device-scope ticket, no spinning -> no co-residency risk)
// combines partials + hinge + atomic sum; 64th finisher writes out. 3
// dispatches -> 2. (2) prep restructured: 8 lanes/row (512 blocks vs 4096),
// 6-shuffle reduce vs 12-deep chain, coalesced float4/ushort4. Tile phase
// itself unchanged from R8 (absmax 0).

#define DDIM   128
#define SPLITS 8
#define MARGIN 0.2f
#define EPS    1e-6f
#define SENT   1e30f

#define CHUNK_PITCH 1056           // 1024 B data + 32 B pad
#define WAVE_SPAN   (8 * CHUNK_PITCH)     // 8 chunks (32 rows) per wave
#define TILE_BYTES  (4 * WAVE_SPAN)       // 33792 B per 128x128 bf16 tile

typedef unsigned short ushort_t;
typedef __attribute__((ext_vector_type(8))) short short8;
typedef __attribute__((ext_vector_type(4))) float f32x4;
typedef __attribute__((ext_vector_type(4))) unsigned short ushort4_t;

__device__ __forceinline__ ushort_t f2bf(float f) {   // fp32 -> bf16 RNE
    unsigned int u = __float_as_uint(f);
    u = (u + 0x7FFFu + ((u >> 16) & 1u)) >> 16;
    return (ushort_t)u;
}

__device__ __forceinline__ void g2lds16(const ushort_t* g, void* lds) {
    // wave-uniform lds base; lane i's 16 B land at lds + i*16
    __builtin_amdgcn_global_load_lds(
        (const __attribute__((address_space(1))) unsigned int*)g,
        (__attribute__((address_space(3))) unsigned int*)lds,
        16, 0, 0);
}

// ---- kernel 1: bf16 convert + exact fp32 row stats + zero control vars ----
// 8 lanes per row: thread (row = tid>>3, seg = tid&7) loads 4 float4s at
// element (seg + it*8)*4 -> every load/store instruction fully coalesced.
// e1b stores bf16(-2*x) (exact scale: exp+1 & sign) so MFMA yields -2*dot.
__global__ void prep_kernel(const float* __restrict__ e1, const float* __restrict__ e2,
                            const int* __restrict__ target,
                            ushort_t* __restrict__ e1b, ushort_t* __restrict__ e2b,
                            float* __restrict__ rowterm,
                            float* __restrict__ cpos, float* __restrict__ cneg,
                            float* __restrict__ redsum, int* __restrict__ ticket,
                            int* __restrict__ rbTicket, int B) {
    if (blockIdx.x == 0) {
        int t = threadIdx.x;
        if (t < B / 128) rbTicket[t] = 0;               // 64 row-block tickets
        else if (t == 64) { redsum[0] = 0.f; redsum[1] = 0.f; }
        else if (t == 65) *ticket = 0;
    }
    int gr  = blockIdx.x * 32 + (threadIdx.x >> 3);     // 0..2B-1
    int seg = threadIdx.x & 7;
    bool first = gr < B;
    int r = first ? gr : gr - B;
    const float* src = (first ? e1 : e2) + (size_t)r * DDIM;
    ushort_t*    dst = (first ? e1b : e2b) + (size_t)r * DDIM;
    const float sc = first ? -2.f : 1.f;
    float s = 0.f, n = 0.f;
    #pragma unroll
    for (int it = 0; it < 4; ++it) {
        int e0 = (seg + it * 8) * 4;
        float4 v = *(const float4*)(src + e0);
        ushort4_t o;
        o.x = f2bf(sc * v.x); o.y = f2bf(sc * v.y);
        o.z = f2bf(sc * v.z); o.w = f2bf(sc * v.w);
        *(ushort4_t*)(dst + e0) = o;
        s += v.x + v.y + v.z + v.w;
        n += v.x * v.x + v.y * v.y + v.z * v.z + v.w * v.w;
    }
    #pragma unroll
    for (int m = 1; m <= 4; m <<= 1) {                  // 8-lane group reduce
        s += __shfl_xor(s, m, 64);
        n += __shfl_xor(n, m, 64);
    }
    if (seg == 0) {
        if (first) {
            rowterm[r] = n + 2.f * EPS * s + (float)DDIM * EPS * EPS;
        } else {
            float ct = n - 2.f * EPS * s;
            int tg = target[r];
            cpos[r] = (tg == 1) ? ct : -SENT;
            cneg[r] = (tg == 0) ? ct :  SENT;
        }
    }
}

// stage a 128x128 bf16 tile via DMA: wave w -> rows [w*32, w*32+32)
__device__ __forceinline__ void stage_tile_dma(const ushort_t* __restrict__ gRow0,
                                               unsigned char* __restrict__ lds,
                                               int w, int l) {
    const ushort_t* g = gRow0 + (size_t)(w * 32) * DDIM + l * 8;
    unsigned char* lp = lds + w * WAVE_SPAN;
    #pragma unroll
    for (int it = 0; it < 8; ++it)
        g2lds16(g + it * 512, lp + it * CHUNK_PITCH);
}

// ---- kernel 2: MFMA tile + fused masked max/min + fused final reduce ----
// grid (B/128, SPLITS), block 256 = 4 waves; 128x128 tile, K=128.
// A frags from global (L2), B double-buffered in LDS, one barrier per tile.
// Tail: last split-block per row-block (ticket, no spin) combines partials.
__global__ __launch_bounds__(256, 2)
void tile_kernel(const ushort_t* __restrict__ e1b, const ushort_t* __restrict__ e2b,
                 const float* __restrict__ cpos, const float* __restrict__ cneg,
                 const float* __restrict__ rowterm, const int* __restrict__ target,
                 float* __restrict__ pmp, float* __restrict__ nmp,
                 int* __restrict__ rbTicket, float* __restrict__ redsum,
                 int* __restrict__ ticket, float* __restrict__ out, int B) {
    __shared__ __align__(16) unsigned char Bs[2][TILE_BYTES];   // 67584 B

    const int tid = threadIdx.x;
    const int w   = tid >> 6;
    const int l   = tid & 63;
    const int lq  = l >> 4;          // quad 0..3
    const int lm  = l & 15;
    const int row0 = blockIdx.x * 128;
    const int colSpan = B / SPLITS;                  // 1024
    const int col0 = blockIdx.y * colSpan;
    const int nTiles = colSpan / 128;                // 8

    const int wr = (w >> 1) * 64;    // wave quadrant in tile
    const int wc = (w & 1) * 64;

    // fragment row R = wc + j*16 + lm; byte addr in buffer =
    //   (R>>2)*1056 + (R&3)*256 + lq*16 + kk*2  (laneBase lane-constant)
    const unsigned char* bLane0 = Bs[0] + ((wc >> 2) + (lm >> 2)) * CHUNK_PITCH
                                        + (lm & 3) * 256 + lq * 16;

    // A fragments straight from global: row = row0+wr+i*16+lm,
    // elems [k4*32 + lq*8, +8). 16 rows x 64 B per load -> L2-friendly.
    const ushort_t* aG = e1b + (size_t)(row0 + wr + lm) * DDIM + lq * 8;
    short8 afr[4][4];                // [i][k4]
    #pragma unroll
    for (int i = 0; i < 4; ++i)
        #pragma unroll
        for (int k4 = 0; k4 < 4; ++k4)
            afr[i][k4] = *(const short8*)(aG + i * 16 * DDIM + k4 * 32);

    stage_tile_dma(e2b + (size_t)col0 * DDIM, Bs[0], w, l);

    float pm[4][4], nm[4][4];        // [i][r]: local row = wr + i*16 + lq*4 + r
    #pragma unroll
    for (int i = 0; i < 4; ++i)
        #pragma unroll
        for (int r = 0; r < 4; ++r) { pm[i][r] = -SENT; nm[i][r] = SENT; }

    __syncthreads();                 // A frags + tile 0 staged (vmcnt drain)

    for (int t = 0; t < nTiles; ++t) {
        // issue next tile's DMA FIRST; it lands under this tile's compute
        if (t + 1 < nTiles)
            stage_tile_dma(e2b + (size_t)(col0 + (t + 1) * 128) * DDIM,
                           Bs[(t + 1) & 1], w, l);

        const unsigned char* bl = bLane0 + (t & 1) * TILE_BYTES;

        f32x4 acc[4][4];
        #pragma unroll
        for (int i = 0; i < 4; ++i)
            #pragma unroll
            for (int j = 0; j < 4; ++j)
                acc[i][j] = (f32x4){0.f, 0.f, 0.f, 0.f};

        #pragma unroll
        for (int kk = 0; kk < DDIM; kk += 32) {
            const int k4 = kk >> 5;
            const int ko = kk * 2;   // byte offset within row
            short8 bf[4];
            #pragma unroll
            for (int j = 0; j < 4; ++j)
                bf[j] = *(const short8*)(bl + j * (4 * CHUNK_PITCH) + ko);
            #pragma unroll
            for (int i = 0; i < 4; ++i)
                #pragma unroll
                for (int j = 0; j < 4; ++j)
                    acc[i][j] = __builtin_amdgcn_mfma_f32_16x16x32_bf16(
                                    afr[i][k4], bf[j], acc[i][j], 0, 0, 0);
        }

        // epilogue: acc already = -2*dot. Pair j's so clang fuses v_max3/v_min3.
        {
            const int colb = col0 + t * 128 + wc + lm;   // C/D: col = lane&15
            #pragma unroll
            for (int jp = 0; jp < 2; ++jp) {
                const int j0 = 2 * jp, j1 = j0 + 1;
                const float cp0 = cpos[colb + j0 * 16], cn0 = cneg[colb + j0 * 16];
                const float cp1 = cpos[colb + j1 * 16], cn1 = cneg[colb + j1 * 16];
                #pragma unroll
                for (int i = 0; i < 4; ++i)
                    #pragma unroll
                    for (int r = 0; r < 4; ++r) {
                        const float d0 = acc[i][j0][r];
                        const float d1 = acc[i][j1][r];
                        pm[i][r] = fmaxf(fmaxf(pm[i][r], d0 + cp0), d1 + cp1);
                        nm[i][r] = fminf(fminf(nm[i][r], d0 + cn0), d1 + cn1);
                    }
            }
        }

        __syncthreads();   // drains stage(t+1) DMA; all waves done with Bs[t&1]
    }

    // intra-wave: reduce across the 16 column-lanes (rows fixed per (lq,r))
    #pragma unroll
    for (int m = 1; m < 16; m <<= 1) {
        #pragma unroll
        for (int i = 0; i < 4; ++i)
            #pragma unroll
            for (int r = 0; r < 4; ++r) {
                pm[i][r] = fmaxf(pm[i][r], __shfl_xor(pm[i][r], m, 64));
                nm[i][r] = fminf(nm[i][r], __shfl_xor(nm[i][r], m, 64));
            }
    }

    // cross-wave: waves (2h, 2h+1) share rows over complementary column
    // halves -> combine via LDS scratch (loop's last barrier already passed).
    float* smP = (float*)Bs;               // [128]
    float* smN = smP + 128;                // [128]
    if ((w & 1) == 1 && lm == 0) {
        #pragma unroll
        for (int i = 0; i < 4; ++i)
            #pragma unroll
            for (int r = 0; r < 4; ++r) {
                int lr = wr + i * 16 + lq * 4 + r;
                smP[lr] = pm[i][r];
                smN[lr] = nm[i][r];
            }
    }
    __syncthreads();
    if ((w & 1) == 0 && lm == 0) {
        #pragma unroll
        for (int i = 0; i < 4; ++i)
            #pragma unroll
            for (int r = 0; r < 4; ++r) {
                int lr  = wr + i * 16 + lq * 4 + r;     // C/D: row = quad*4+reg
                int row = row0 + lr;
                pmp[(size_t)blockIdx.y * B + row] = fmaxf(pm[i][r], smP[lr]);
                nmp[(size_t)blockIdx.y * B + row] = fminf(nm[i][r], smN[lr]);
            }
    }

    // ---- fused reduce tail: last split-block for this row-block finishes ----
    __shared__ int lastrb;
    __syncthreads();                 // partial stores drained (vmcnt0 + barrier)
    if (tid == 0) {
        __threadfence();             // release: writeback this XCD's L2
        int prev = __hip_atomic_fetch_add(&rbTicket[blockIdx.x], 1,
                       __ATOMIC_ACQ_REL, __HIP_MEMORY_SCOPE_AGENT);
        lastrb = (prev == SPLITS - 1);
    }
    __syncthreads();
    if (!lastrb) return;

    float s = 0.f, c = 0.f;
    if (tid < 128) {
        int row = row0 + tid;
        float pmv = -SENT, nmv = SENT;
        #pragma unroll
        for (int sp = 0; sp < SPLITS; ++sp) {   // agent-scope loads: skip stale L1/L2
            pmv = fmaxf(pmv, __hip_atomic_load(&pmp[(size_t)sp * B + row],
                              __ATOMIC_RELAXED, __HIP_MEMORY_SCOPE_AGENT));
            nmv = fminf(nmv, __hip_atomic_load(&nmp[(size_t)sp * B + row],
                              __ATOMIC_RELAXED, __HIP_MEMORY_SCOPE_AGENT));
        }
        float rt = rowterm[row];
        float dp = sqrtf(fmaxf(rt + pmv, 0.f));
        float dn = sqrtf(fmaxf(rt + nmv, 0.f));
        if (target[row] == 1) {
            s = fmaxf(dp - dn + MARGIN, 0.f);
            c = 1.f;
        }
    }
    #pragma unroll
    for (int off = 32; off > 0; off >>= 1) {
        s += __shfl_down(s, off, 64);
        c += __shfl_down(c, off, 64);
    }
    __shared__ float ls[4], lc[4];
    if (l == 0) { ls[w] = s; lc[w] = c; }
    __syncthreads();
    if (tid == 0) {
        float ss = ls[0] + ls[1] + ls[2] + ls[3];
        float cc = lc[0] + lc[1] + lc[2] + lc[3];
        atomicAdd(&redsum[0], ss);
        atomicAdd(&redsum[1], cc);
        __threadfence();
        int done = atomicAdd(ticket, 1);
        if (done == (B / 128) - 1) {            // 64th finisher writes out
            __threadfence();
            float fs = __hip_atomic_load(&redsum[0], __ATOMIC_RELAXED, __HIP_MEMORY_SCOPE_AGENT);
            float fc = __hip_atomic_load(&redsum[1], __ATOMIC_RELAXED, __HIP_MEMORY_SCOPE_AGENT);
            out[0] = fs / fc;
        }
    }
}

extern "C" void kernel_launch(void* const* d_in, const int* in_sizes, int n_in,
                              void* d_out, int out_size, void* d_ws, size_t ws_size,
                              hipStream_t stream) {
    const float* e1     = (const float*)d_in[0];
    const float* e2     = (const float*)d_in[1];
    const int*   target = (const int*)d_in[2];
    float* out = (float*)d_out;
    const int B = in_sizes[2];                       // 8192

    // ws layout: e1b | e2b | rowterm | cpos | cneg | pmp | nmp | redsum | ticket | rbTicket
    char* p = (char*)d_ws;
    ushort_t* e1b  = (ushort_t*)p;   p += (size_t)B * DDIM * 2;   // 2 MB (scaled by -2)
    ushort_t* e2b  = (ushort_t*)p;   p += (size_t)B * DDIM * 2;   // 2 MB
    float* rowterm = (float*)p;      p += (size_t)B * 4;
    float* cpos    = (float*)p;      p += (size_t)B * 4;
    float* cneg    = (float*)p;      p += (size_t)B * 4;
    float* pmp     = (float*)p;      p += (size_t)SPLITS * B * 4;
    float* nmp     = (float*)p;      p += (size_t)SPLITS * B * 4;
    float* redsum  = (float*)p;      p += 2 * 4;
    int*   ticket  = (int*)p;        p += 4;
    int*   rbTicket= (int*)p;        p += (size_t)(B / 128) * 4;

    {   // prep: 8 lanes/row, 32 rows/block -> 2B/32 = 512 blocks
        int blocks = (2 * B) / 32;
        prep_kernel<<<blocks, 256, 0, stream>>>(e1, e2, target, e1b, e2b,
                                                rowterm, cpos, cneg,
                                                redsum, ticket, rbTicket, B);
    }
    {   // 64 row-blocks x 8 col-splits = 512 blocks = 2/CU (66 KB LDS)
        dim3 grid(B / 128, SPLITS);
        tile_kernel<<<grid, 256, 0, stream>>>(e1b, e2b, cpos, cneg,
                                              rowterm, target, pmp, nmp,
                                              rbTicket, redsum, ticket, out, B);
    }
}